// Round 9
// baseline (949.288 us; speedup 1.0000x reference)
//
#include <hip/hip_runtime.h>
#include <math.h>

#define NN 50000
#define NE 800000
#define F_IN 11
#define HID 128
#define NEG_SLOPE 0.2f

typedef __attribute__((ext_vector_type(8))) short short8;
typedef __attribute__((ext_vector_type(4))) float f32x4;

__device__ __forceinline__ float bf2f(ushort u) {
  return __uint_as_float(((unsigned)u) << 16);
}
__device__ __forceinline__ ushort f2bf(float f) {
  unsigned u = __float_as_uint(f);
  return (ushort)((u + 0x7fff + ((u >> 16) & 1)) >> 16);
}
__device__ __forceinline__ float lrelu(float x) { return x > 0.f ? x : NEG_SLOPE * x; }
__device__ __forceinline__ float elu1(float x) { return x > 0.f ? x : expm1f(x); }

// finite "-inf": online-softmax merges of empty lanes must never form inf-inf=NaN
#define MNEG (-1e30f)

// order own-wave ds_writes before cross-lane ds_reads (no cross-wave sync needed)
__device__ __forceinline__ void wave_fence() {
  asm volatile("s_waitcnt lgkmcnt(0)" ::: "memory");
}

#define AS1 __attribute__((address_space(1)))
#define AS3 __attribute__((address_space(3)))

// ---------- prep: Wt2/Wt3 transpose+bf16, zero deg + gpart (one kernel) ----------
__global__ __launch_bounds__(256) void k_prep(const float* __restrict__ W2,
                                              const float* __restrict__ W3,
                                              ushort* __restrict__ Wt2,
                                              ushort* __restrict__ Wt3,
                                              int* __restrict__ deg,
                                              float* __restrict__ gpart) {
  __shared__ float tl[32][33];
  int b = blockIdx.x, t = threadIdx.x;
  int tx = t & 31, ty = t >> 5;
  if (b < 256) {  // Wt2: K=512, N=512
    int bn = (b & 15) * 32, bk = (b >> 4) * 32;
    for (int i = ty; i < 32; i += 8) tl[i][tx] = W2[(size_t)(bk + i) * 512 + bn + tx];
    __syncthreads();
    for (int i = ty; i < 32; i += 8)
      Wt2[(size_t)(bn + i) * 512 + bk + tx] = f2bf(tl[tx][i]);
  } else if (b < 320) {  // Wt3: K=512, N=128
    int bb = b - 256;
    int bn = (bb & 3) * 32, bk = (bb >> 2) * 32;
    for (int i = ty; i < 32; i += 8) tl[i][tx] = W3[(size_t)(bk + i) * 128 + bn + tx];
    __syncthreads();
    for (int i = ty; i < 32; i += 8)
      Wt3[(size_t)(bn + i) * 512 + bk + tx] = f2bf(tl[tx][i]);
  } else {  // zero deg (196 blocks) + gpart (first 32 blocks)
    int b2 = b - 320;
    int idx = b2 * 256 + t;
    if (idx < NN) deg[idx] = 0;
    if (b2 < 32) gpart[b2 * 256 + t] = 0.f;
  }
}

// ---------- CSR build ----------
__global__ void k_deg(const int* __restrict__ ei, int* __restrict__ deg) {
  int e = blockIdx.x * blockDim.x + threadIdx.x;
  if (e < NE) atomicAdd(&deg[ei[NE + e]], 1);
}

__global__ void k_scan(const int* __restrict__ deg, int* __restrict__ row_ptr,
                       int* __restrict__ cursor) {
  const int T = 1024;
  const int CH = (NN + T - 1) / T;
  __shared__ int ssum[T];
  int t = threadIdx.x;
  int base = t * CH;
  int s = 0;
  for (int i = 0; i < CH; i++) {
    int idx = base + i;
    if (idx < NN) s += deg[idx];
  }
  ssum[t] = s;
  __syncthreads();
  for (int off = 1; off < T; off <<= 1) {
    int v = (t >= off) ? ssum[t - off] : 0;
    __syncthreads();
    ssum[t] += v;
    __syncthreads();
  }
  int run = ssum[t] - s;
  for (int i = 0; i < CH; i++) {
    int idx = base + i;
    if (idx < NN) {
      row_ptr[idx] = run;
      cursor[idx] = run;
      run += deg[idx];
    }
  }
  if (t == 0) row_ptr[NN] = ssum[T - 1];
}

__global__ void k_scatter(const int* __restrict__ ei, int* __restrict__ cursor,
                          int* __restrict__ csr_src) {
  int e = blockIdx.x * blockDim.x + threadIdx.x;
  if (e < NE) {
    int d = ei[NE + e];
    int pos = atomicAdd(&cursor[d], 1);
    csr_src[pos] = ei[e];
  }
}

// ---------- layer 1: per-node attention scores from raw x (vsd inlined) ----------
__global__ __launch_bounds__(256) void k_axv(const float* __restrict__ x,
                                             const float* __restrict__ W1,
                                             const float* __restrict__ as1,
                                             const float* __restrict__ ad1,
                                             float* __restrict__ asrc,
                                             float* __restrict__ adst) {
  __shared__ float svs[44], svd[44];
  int t = threadIdx.x;
  if (t < 88) {  // collapsed vectors v_s/v_d[k][h] = sum_c W1[k,h*128+c]*a[h,c]
    int side = t & 1, kh = t >> 1;
    int k = kh >> 2, h = kh & 3;
    const float* av = side ? ad1 : as1;
    float s = 0.f;
    for (int c = 0; c < HID; c++) s += W1[k * 512 + h * HID + c] * av[h * HID + c];
    if (side)
      svd[kh] = s;
    else
      svs[kh] = s;
  }
  __syncthreads();
  int n = blockIdx.x * 256 + t;
  if (n >= NN) return;
  float xr[F_IN];
#pragma unroll
  for (int k = 0; k < F_IN; k++) xr[k] = x[n * F_IN + k];
  float s[4] = {}, dd[4] = {};
#pragma unroll
  for (int k = 0; k < F_IN; k++)
#pragma unroll
    for (int h = 0; h < 4; h++) {
      s[h] += xr[k] * svs[k * 4 + h];
      dd[h] += xr[k] * svd[k * 4 + h];
    }
  *(f32x4*)(asrc + n * 4) = f32x4{s[0], s[1], s[2], s[3]};
  *(f32x4*)(adst + n * 4) = f32x4{dd[0], dd[1], dd[2], dd[3]};
}

// ---------- layer 1: aggregate RAW x -> P (in LDS) -> out = elu(P@W1 + b1) ----------
__global__ __launch_bounds__(256) void k_aggpre(
    const float* __restrict__ x, const float* __restrict__ asrc,
    const float* __restrict__ adst, const int* __restrict__ row_ptr,
    const int* __restrict__ csr_src, const float* __restrict__ W1,
    const float* __restrict__ b1, ushort* __restrict__ out) {
  const int CAP = 64;
  __shared__ float sW[F_IN * 512];  // 22.5 KB
  __shared__ int src_c[4][CAP];
  __shared__ float ea[4][CAP * 4];
  __shared__ float sP[4][44];
  int t = threadIdx.x, lane = t & 63, wv = t >> 6;
  for (int i = t; i < F_IN * 512; i += 256) sW[i] = W1[i];  // used after barrier
  int d = blockIdx.x * 4 + wv;
  int start = row_ptr[d], deg = row_ptr[d + 1] - start;
  int dcap = min(deg, CAP);
  for (int i = lane; i < dcap; i += 64) src_c[wv][i] = csr_src[start + i];
  wave_fence();
  int hh = lane & 3;
  float adh = adst[d * 4 + hh];
  float m = MNEG, s = 0.f;
  int deg4 = deg * 4;
  for (int i = lane; i < deg4; i += 64) {
    int k = i >> 2;
    int sn = (k < CAP) ? src_c[wv][k] : csr_src[start + k];
    float v = lrelu(asrc[sn * 4 + hh] + adh);
    if (k < CAP) ea[wv][i] = v;
    float nm = fmaxf(m, v);
    s = s * __expf(m - nm) + __expf(v - nm);
    m = nm;
  }
#pragma unroll
  for (int off = 4; off < 64; off <<= 1) {
    float m2 = __shfl_xor(m, off);
    float s2 = __shfl_xor(s, off);
    float nm = fmaxf(m, m2);
    s = s * __expf(m - nm) + s2 * __expf(m2 - nm);
    m = nm;
  }
  float sinv = (s > 0.f) ? 1.f / s : 0.f;
  int dc4 = dcap * 4;
  for (int i = lane; i < dc4; i += 64) ea[wv][i] = __expf(ea[wv][i] - m) * sinv;
  wave_fence();
  // pass 2: lanes 0..43 own (h,k); unroll-4 edges
  int hq = lane / F_IN;
  int k = lane - hq * F_IN;
  int h = hq & 3;
  float mh = __shfl(m, h), sih = __shfl(sinv, h);
  float adh2 = adst[d * 4 + h];
  float acc = 0.f;
#define GETP(i, SN, A)                                                \
  do {                                                                \
    int kk_ = e + (i);                                                \
    if (kk_ < CAP) {                                                  \
      SN = src_c[wv][kk_];                                            \
      A = ea[wv][kk_ * 4 + h];                                        \
    } else {                                                          \
      SN = csr_src[start + kk_];                                      \
      A = __expf(lrelu(asrc[SN * 4 + h] + adh2) - mh) * sih;          \
    }                                                                 \
  } while (0)
  int e = 0;
  for (; e + 4 <= deg; e += 4) {
    int sn0, sn1, sn2, sn3;
    float a0, a1, a2, a3;
    GETP(0, sn0, a0);
    GETP(1, sn1, a1);
    GETP(2, sn2, a2);
    GETP(3, sn3, a3);
    float x0 = x[sn0 * F_IN + k];
    float x1 = x[sn1 * F_IN + k];
    float x2 = x[sn2 * F_IN + k];
    float x3 = x[sn3 * F_IN + k];
    acc += a0 * x0 + a1 * x1 + a2 * x2 + a3 * x3;
  }
  for (; e < deg; e++) {
    int sn;
    float a;
    GETP(0, sn, a);
    acc += a * x[sn * F_IN + k];
  }
#undef GETP
  if (lane < 44) sP[wv][lane] = acc;
  __syncthreads();  // sP + sW ready
  // fused layer-1 GEMM: thread -> node (wv), cols lane*8..+7 (one head per lane)
  int j0 = lane * 8;
  int hj = j0 >> 7;
  float pv[F_IN];
#pragma unroll
  for (int kk = 0; kk < F_IN; kk++) pv[kk] = sP[wv][hj * F_IN + kk];
  float o[8];
#pragma unroll
  for (int jj = 0; jj < 8; jj++) o[jj] = b1[j0 + jj];
#pragma unroll
  for (int kk = 0; kk < F_IN; kk++) {
    float4 wa = *(const float4*)&sW[kk * 512 + j0];
    float4 wb = *(const float4*)&sW[kk * 512 + j0 + 4];
    float p = pv[kk];
    o[0] += p * wa.x;
    o[1] += p * wa.y;
    o[2] += p * wa.z;
    o[3] += p * wa.w;
    o[4] += p * wb.x;
    o[5] += p * wb.y;
    o[6] += p * wb.z;
    o[7] += p * wb.w;
  }
  unsigned pk[4];
#pragma unroll
  for (int j = 0; j < 4; j++) {
    float e0 = elu1(o[2 * j]);
    float e1 = elu1(o[2 * j + 1]);
    pk[j] = (unsigned)f2bf(e0) | ((unsigned)f2bf(e1) << 16);
  }
  *(uint4*)(out + (size_t)d * 512 + j0) = make_uint4(pk[0], pk[1], pk[2], pk[3]);
}

// ---------- bf16 MFMA GEMM: C[M,N] = A[M,K] @ Bt[N,K]^T ----------
#define TM 128
#define TN 128
#define TK 64
__global__ __launch_bounds__(256) void k_mfma(const ushort* __restrict__ A,
                                              const ushort* __restrict__ Bt,
                                              ushort* __restrict__ C,
                                              int M, int N, int K, int H) {
  __shared__ ushort lds[TM * TK + TN * TK];
  ushort* As = lds;
  ushort* Bs = lds + TM * TK;
  int tid = threadIdx.x;
  int lane = tid & 63, wv = tid >> 6;
  int wr = wv >> 1, wc = wv & 1;
  int nwg = gridDim.x;
  int q = nwg >> 3, rr = nwg & 7;
  int xcd = blockIdx.x & 7, off8 = blockIdx.x >> 3;
  int lid = (xcd < rr ? xcd * (q + 1) : rr * (q + 1) + (xcd - rr) * q) + off8;
  int bm = lid / H, hy = lid - bm * H;
  int bm0 = bm * TM, bn0 = hy * TN;
  int l15 = lane & 15, l4 = lane >> 4;
  f32x4 acc[4][4] = {};
  for (int k0 = 0; k0 < K; k0 += TK) {
#pragma unroll
    for (int it = 0; it < 4; ++it) {
      int chunk = it * 4 + wv;
      int pbase = chunk * 1024;
      int p = pbase + lane * 16;
      int prow = p >> 7;
      int lblk = ((p >> 4) & 7) ^ (prow & 7);
      int gr = bm0 + prow;
      gr = gr < M ? gr : M - 1;
      __builtin_amdgcn_global_load_lds(
          (const AS1 void*)(A + (size_t)gr * K + (k0 + lblk * 8)),
          (AS3 void*)((char*)As + pbase), 16, 0, 0);
      int gb = bn0 + prow;
      __builtin_amdgcn_global_load_lds(
          (const AS1 void*)(Bt + (size_t)gb * K + (k0 + lblk * 8)),
          (AS3 void*)((char*)Bs + pbase), 16, 0, 0);
    }
    __syncthreads();
#pragma unroll
    for (int kk = 0; kk < 2; ++kk) {
      int cb = kk * 4 + l4;
      short8 af[4], bfr[4];
#pragma unroll
      for (int m = 0; m < 4; ++m) {
        int row = wr * 64 + m * 16 + l15;
        af[m] = *(const short8*)((const char*)As + row * 128 + ((cb ^ (row & 7)) << 4));
      }
#pragma unroll
      for (int n = 0; n < 4; ++n) {
        int row = wc * 64 + n * 16 + l15;
        bfr[n] = *(const short8*)((const char*)Bs + row * 128 + ((cb ^ (row & 7)) << 4));
      }
#pragma unroll
      for (int m = 0; m < 4; ++m)
#pragma unroll
        for (int n = 0; n < 4; ++n)
          acc[m][n] = __builtin_amdgcn_mfma_f32_16x16x32_bf16(af[m], bfr[n], acc[m][n], 0, 0, 0);
    }
    __syncthreads();
  }
#pragma unroll
  for (int m = 0; m < 4; ++m) {
#pragma unroll
    for (int r = 0; r < 4; ++r) {
      int row = bm0 + wr * 64 + m * 16 + l4 * 4 + r;
      if (row < M) {
#pragma unroll
        for (int n = 0; n < 4; ++n) {
          int col = bn0 + wc * 64 + n * 16 + l15;
          C[(size_t)row * N + col] = f2bf(acc[m][n][r]);
        }
      }
    }
  }
}

// ---------- attention coefficients from transformed features (layers 2,3) ----------
template <int H>
__global__ void k_alpha(const ushort* __restrict__ h, const float* __restrict__ a_src,
                        const float* __restrict__ a_dst, float* __restrict__ asrc,
                        float* __restrict__ adst) {
  int t = threadIdx.x;  // 256
  int lane = t & 63;
  int n_g, h_g;
  if (H == 4) {
    n_g = blockIdx.x * 4 + (t >> 6);
    h_g = lane >> 4;
  } else {
    n_g = blockIdx.x * 16 + (t >> 4);
    h_g = 0;
  }
  if (n_g >= NN) return;
  int cl = lane & 15;
  short8 hv = *(const short8*)(h + (size_t)n_g * (H * 128) + h_g * 128 + cl * 8);
  const float* as = a_src + h_g * 128 + cl * 8;
  const float* ad = a_dst + h_g * 128 + cl * 8;
  float s1 = 0.f, s2 = 0.f;
#pragma unroll
  for (int j = 0; j < 8; j++) {
    float v = bf2f((ushort)hv[j]);
    s1 += v * as[j];
    s2 += v * ad[j];
  }
#pragma unroll
  for (int off = 1; off < 16; off <<= 1) {
    s1 += __shfl_xor(s1, off);
    s2 += __shfl_xor(s2, off);
  }
  if (cl == 0) {
    asrc[n_g * H + h_g] = s1;
    adst[n_g * H + h_g] = s2;
  }
}

// ---------- layer-2 aggregate: wave-per-node, H=4, unroll-2 gather ----------
// (unroll-2 is the sweet spot: 28 VGPR / ~86% occupancy; unroll-4 was 48 VGPR
//  / 51% occupancy and 10us slower — round-7 post-mortem)
__global__ __launch_bounds__(256) void k_agg4w(
    const ushort* __restrict__ h, const float* __restrict__ asrc,
    const float* __restrict__ adst, const int* __restrict__ row_ptr,
    const int* __restrict__ csr_src, const float* __restrict__ bias,
    ushort* __restrict__ out) {
  const int CAP = 64;
  __shared__ int src_c[4][CAP];
  __shared__ float ea[4][CAP * 4];
  int t = threadIdx.x, lane = t & 63, wv = t >> 6;
  int d = blockIdx.x * 4 + wv;
  int start = row_ptr[d], deg = row_ptr[d + 1] - start;
  int dcap = min(deg, CAP);
  for (int i = lane; i < dcap; i += 64) src_c[wv][i] = csr_src[start + i];
  wave_fence();
  int hh = lane & 3;
  float adh = adst[d * 4 + hh];
  float m = MNEG, s = 0.f;
  int deg4 = deg * 4;
  for (int i = lane; i < deg4; i += 64) {
    int k = i >> 2;
    int sn = (k < CAP) ? src_c[wv][k] : csr_src[start + k];
    float v = lrelu(asrc[sn * 4 + hh] + adh);
    if (k < CAP) ea[wv][i] = v;
    float nm = fmaxf(m, v);
    s = s * __expf(m - nm) + __expf(v - nm);
    m = nm;
  }
#pragma unroll
  for (int off = 4; off < 64; off <<= 1) {
    float m2 = __shfl_xor(m, off);
    float s2 = __shfl_xor(s, off);
    float nm = fmaxf(m, m2);
    s = s * __expf(m - nm) + s2 * __expf(m2 - nm);
    m = nm;
  }
  float sinv = (s > 0.f) ? 1.f / s : 0.f;
  int dc4 = dcap * 4;
  for (int i = lane; i < dc4; i += 64) ea[wv][i] = __expf(ea[wv][i] - m) * sinv;
  wave_fence();
  int hl = lane >> 4;
  float mh = __shfl(m, hl), sih = __shfl(sinv, hl);
  float adh2 = adst[d * 4 + hl];
  float acc0[8] = {}, acc1[8] = {};
  int k = 0;
  for (; k + 2 <= deg; k += 2) {
    int sn0, sn1;
    float a0, a1;
    if (k < CAP) {
      sn0 = src_c[wv][k];
      a0 = ea[wv][k * 4 + hl];
    } else {
      sn0 = csr_src[start + k];
      a0 = __expf(lrelu(asrc[sn0 * 4 + hl] + adh2) - mh) * sih;
    }
    if (k + 1 < CAP) {
      sn1 = src_c[wv][k + 1];
      a1 = ea[wv][(k + 1) * 4 + hl];
    } else {
      sn1 = csr_src[start + k + 1];
      a1 = __expf(lrelu(asrc[sn1 * 4 + hl] + adh2) - mh) * sih;
    }
    short8 v0 = *(const short8*)(h + (size_t)sn0 * 512 + lane * 8);
    short8 v1 = *(const short8*)(h + (size_t)sn1 * 512 + lane * 8);
#pragma unroll
    for (int j = 0; j < 8; j++) acc0[j] += a0 * bf2f((ushort)v0[j]);
#pragma unroll
    for (int j = 0; j < 8; j++) acc1[j] += a1 * bf2f((ushort)v1[j]);
  }
  if (k < deg) {
    int sn;
    float a;
    if (k < CAP) {
      sn = src_c[wv][k];
      a = ea[wv][k * 4 + hl];
    } else {
      sn = csr_src[start + k];
      a = __expf(lrelu(asrc[sn * 4 + hl] + adh2) - mh) * sih;
    }
    short8 v0 = *(const short8*)(h + (size_t)sn * 512 + lane * 8);
#pragma unroll
    for (int j = 0; j < 8; j++) acc0[j] += a * bf2f((ushort)v0[j]);
  }
  const float* bp = bias + lane * 8;
  unsigned pk[4];
#pragma unroll
  for (int j = 0; j < 4; j++) {
    float o0 = elu1(acc0[2 * j] + acc1[2 * j] + bp[2 * j]);
    float o1 = elu1(acc0[2 * j + 1] + acc1[2 * j + 1] + bp[2 * j + 1]);
    pk[j] = (unsigned)f2bf(o0) | ((unsigned)f2bf(o1) << 16);
  }
  *(uint4*)(out + (size_t)d * 512 + lane * 8) = make_uint4(pk[0], pk[1], pk[2], pk[3]);
}

// ---------- layer-3 aggregate: 16-lane x 4-slot, 16B loads, + graph-sum fusion ----------
__global__ __launch_bounds__(256) void k_agg1w(
    const ushort* __restrict__ h, const float* __restrict__ asrc,
    const float* __restrict__ adst, const int* __restrict__ row_ptr,
    const int* __restrict__ csr_src, const float* __restrict__ bias,
    ushort* __restrict__ out, float* __restrict__ gpart) {
  const int CAP = 64;
  __shared__ int src_c[4][CAP];
  __shared__ float ea[4][CAP];
  int t = threadIdx.x, lane = t & 63, wv = t >> 6;
  int slot = lane >> 4, cl = lane & 15;
  int d = blockIdx.x * 4 + wv;
  int start = row_ptr[d], deg = row_ptr[d + 1] - start;
  int dcap = min(deg, CAP);
  for (int i = lane; i < dcap; i += 64) src_c[wv][i] = csr_src[start + i];
  wave_fence();
  float adh = adst[d];
  float m = MNEG, s = 0.f;
  for (int i = lane; i < deg; i += 64) {
    int sn = (i < CAP) ? src_c[wv][i] : csr_src[start + i];
    float v = lrelu(asrc[sn] + adh);
    if (i < CAP) ea[wv][i] = v;
    float nm = fmaxf(m, v);
    s = s * __expf(m - nm) + __expf(v - nm);
    m = nm;
  }
#pragma unroll
  for (int off = 1; off < 64; off <<= 1) {
    float m2 = __shfl_xor(m, off);
    float s2 = __shfl_xor(s, off);
    float nm = fmaxf(m, m2);
    s = s * __expf(m - nm) + s2 * __expf(m2 - nm);
    m = nm;
  }
  float sinv = (s > 0.f) ? 1.f / s : 0.f;
  for (int i = lane; i < dcap; i += 64) ea[wv][i] = __expf(ea[wv][i] - m) * sinv;
  wave_fence();
#define GET1(KK, SN, A)                                               \
  do {                                                                \
    if ((KK) < CAP) {                                                 \
      SN = src_c[wv][KK];                                             \
      A = ea[wv][KK];                                                 \
    } else {                                                          \
      SN = csr_src[start + (KK)];                                     \
      A = __expf(lrelu(asrc[SN] + adh) - m) * sinv;                   \
    }                                                                 \
  } while (0)
  float acc0[8] = {}, acc1[8] = {};
  int k = slot;
  for (; k + 4 < deg; k += 8) {
    int sn0, sn1;
    float a0, a1;
    GET1(k, sn0, a0);
    GET1(k + 4, sn1, a1);
    short8 v0 = *(const short8*)(h + (size_t)sn0 * 128 + cl * 8);
    short8 v1 = *(const short8*)(h + (size_t)sn1 * 128 + cl * 8);
#pragma unroll
    for (int j = 0; j < 8; j++) acc0[j] += a0 * bf2f((ushort)v0[j]);
#pragma unroll
    for (int j = 0; j < 8; j++) acc1[j] += a1 * bf2f((ushort)v1[j]);
  }
  for (; k < deg; k += 4) {
    int sn;
    float a;
    GET1(k, sn, a);
    short8 v0 = *(const short8*)(h + (size_t)sn * 128 + cl * 8);
#pragma unroll
    for (int j = 0; j < 8; j++) acc0[j] += a * bf2f((ushort)v0[j]);
  }
#undef GET1
#pragma unroll
  for (int j = 0; j < 8; j++) {
    float v = acc0[j] + acc1[j];
    v += __shfl_xor(v, 16);
    v += __shfl_xor(v, 32);
    acc0[j] = v;
  }
  if (slot == 0) {
    const float* bp = bias + cl * 8;
    float ov[8];
#pragma unroll
    for (int j = 0; j < 8; j++) ov[j] = acc0[j] + bp[j];
    unsigned pk[4];
#pragma unroll
    for (int j = 0; j < 4; j++)
      pk[j] = (unsigned)f2bf(ov[2 * j]) | ((unsigned)f2bf(ov[2 * j + 1]) << 16);
    *(uint4*)(out + (size_t)d * 128 + cl * 8) = make_uint4(pk[0], pk[1], pk[2], pk[3]);
    // graph-mean partial accumulation (64 replicas to spread atomic contention)
    float* gp = gpart + (blockIdx.x & 63) * 128 + cl * 8;
#pragma unroll
    for (int j = 0; j < 8; j++) atomicAdd(&gp[j], ov[j]);
  }
}

// ---------- heads (graph mean reduced from gpart replicas) ----------
__global__ void k_head(const float* __restrict__ gpart, const ushort* __restrict__ h3,
                       const int* __restrict__ curp, const float* __restrict__ pw1,
                       const float* __restrict__ pb1, const float* __restrict__ pw2,
                       const float* __restrict__ pb2, const float* __restrict__ vw1,
                       const float* __restrict__ vb1, const float* __restrict__ vw2,
                       const float* __restrict__ vb2, float* __restrict__ outp) {
  __shared__ float comb[HID], ph[HID], vh[HID];
  int t = threadIdx.x;  // 128
  int cur = curp[0];
  float gs = 0.f;
#pragma unroll 8
  for (int r = 0; r < 64; r++) gs += gpart[r * 128 + t];
  comb[t] = gs * (1.f / NN) + bf2f(h3[(size_t)cur * HID + t]);
  __syncthreads();
  float accp = pb1[t], accv = vb1[t];
  for (int k = 0; k < HID; k++) {
    float cv = comb[k];
    accp += cv * pw1[k * HID + t];
    accv += cv * vw1[k * HID + t];
  }
  ph[t] = fmaxf(accp, 0.f);
  vh[t] = fmaxf(accv, 0.f);
  __syncthreads();
  if (t < 6) {
    float a = pb2[t];
    for (int k = 0; k < HID; k++) a += ph[k] * pw2[k * 6 + t];
    outp[t] = a;
  }
  if (t == 6) {
    float a = vb2[0];
    for (int k = 0; k < HID; k++) a += vh[k] * vw2[k];
    outp[6] = a;
  }
}

extern "C" void kernel_launch(void* const* d_in, const int* in_sizes, int n_in,
                              void* d_out, int out_size, void* d_ws, size_t ws_size,
                              hipStream_t stream) {
  const float* x = (const float*)d_in[0];
  const int* ei = (const int*)d_in[1];
  const int* cur = (const int*)d_in[2];
  const float* W1 = (const float*)d_in[3];
  const float* as1 = (const float*)d_in[4];
  const float* ad1 = (const float*)d_in[5];
  const float* b1 = (const float*)d_in[6];
  const float* W2 = (const float*)d_in[7];
  const float* as2 = (const float*)d_in[8];
  const float* ad2 = (const float*)d_in[9];
  const float* b2 = (const float*)d_in[10];
  const float* W3 = (const float*)d_in[11];
  const float* as3 = (const float*)d_in[12];
  const float* ad3 = (const float*)d_in[13];
  const float* b3 = (const float*)d_in[14];
  const float* pw1 = (const float*)d_in[15];
  const float* pb1 = (const float*)d_in[16];
  const float* pw2 = (const float*)d_in[17];
  const float* pb2 = (const float*)d_in[18];
  const float* vw1 = (const float*)d_in[19];
  const float* vb1 = (const float*)d_in[20];
  const float* vw2 = (const float*)d_in[21];
  const float* vb2 = (const float*)d_in[22];
  float* out = (float*)d_out;

  char* w = (char*)d_ws;
  ushort* G = (ushort*)w;    w += (size_t)NN * 512 * 2;
  ushort* Abuf = (ushort*)w; w += (size_t)NN * 512 * 2;
  ushort* Wt2 = (ushort*)w;  w += (size_t)512 * 512 * 2;
  ushort* Wt3 = (ushort*)w;  w += (size_t)128 * 512 * 2;
  float* asrc = (float*)w;   w += (size_t)NN * 4 * 4;
  float* adst = (float*)w;   w += (size_t)NN * 4 * 4;
  int* deg = (int*)w;        w += (size_t)NN * 4;
  int* cursor = (int*)w;     w += (size_t)NN * 4;
  int* row_ptr = (int*)w;    w += (size_t)(NN + 1) * 4;
  int* csr_src = (int*)w;    w += (size_t)NE * 4;
  float* gpart = (float*)w;  w += (size_t)64 * 128 * 4;

  // prep: Wt2 (256 blocks) + Wt3 (64) + zero deg/gpart (196)
  k_prep<<<516, 256, 0, stream>>>(W2, W3, Wt2, Wt3, deg, gpart);

  // CSR
  k_deg<<<(NE + 255) / 256, 256, 0, stream>>>(ei, deg);
  k_scan<<<1, 1024, 0, stream>>>(deg, row_ptr, cursor);
  k_scatter<<<(NE + 255) / 256, 256, 0, stream>>>(ei, cursor, csr_src);

  const int GB = (NN + TM - 1) / TM;  // 391

  // Layer 1: scores from raw x, aggregate raw x, fused 11->512 GEMM + ELU
  k_axv<<<(NN + 255) / 256, 256, 0, stream>>>(x, W1, as1, ad1, asrc, adst);
  k_aggpre<<<NN / 4, 256, 0, stream>>>(x, asrc, adst, row_ptr, csr_src, W1, b1, Abuf);

  // Layer 2: bf16 MFMA, alpha, wave-per-node aggregate
  k_mfma<<<GB * 4, 256, 0, stream>>>(Abuf, Wt2, G, NN, 512, 512, 4);
  k_alpha<4><<<(NN + 3) / 4, 256, 0, stream>>>(G, as2, ad2, asrc, adst);
  k_agg4w<<<NN / 4, 256, 0, stream>>>(G, asrc, adst, row_ptr, csr_src, b2, Abuf);

  // Layer 3: bf16 MFMA, alpha, aggregate + graph-sum fusion
  k_mfma<<<GB, 256, 0, stream>>>(Abuf, Wt3, G, NN, 128, 512, 1);
  k_alpha<1><<<(NN + 15) / 16, 256, 0, stream>>>(G, as3, ad3, asrc, adst);
  k_agg1w<<<NN / 4, 256, 0, stream>>>(G, asrc, adst, row_ptr, csr_src, b3, Abuf, gpart);

  // Heads
  k_head<<<1, 128, 0, stream>>>(gpart, Abuf, cur, pw1, pb1, pw2, pb2, vw1, vb1, vw2, vb2, out);
}

// Round 12
// 679.851 us; speedup vs baseline: 1.3963x; 1.3963x over previous
//
#include <hip/hip_runtime.h>
#include <math.h>

#define NN 50000
#define NE 800000
#define F_IN 11
#define HID 128
#define NEG_SLOPE 0.2f

typedef __attribute__((ext_vector_type(8))) short short8;
typedef __attribute__((ext_vector_type(4))) float f32x4;

__device__ __forceinline__ float bf2f(ushort u) {
  return __uint_as_float(((unsigned)u) << 16);
}
__device__ __forceinline__ ushort f2bf(float f) {
  unsigned u = __float_as_uint(f);
  return (ushort)((u + 0x7fff + ((u >> 16) & 1)) >> 16);
}
__device__ __forceinline__ float lrelu(float x) { return x > 0.f ? x : NEG_SLOPE * x; }
__device__ __forceinline__ float elu1(float x) { return x > 0.f ? x : expm1f(x); }

// finite "-inf": online-softmax merges of empty lanes must never form inf-inf=NaN
#define MNEG (-1e30f)

// order own-wave ds_writes before cross-lane ds_reads (no cross-wave sync needed)
__device__ __forceinline__ void wave_fence() {
  asm volatile("s_waitcnt lgkmcnt(0)" ::: "memory");
}

#define AS1 __attribute__((address_space(1)))
#define AS3 __attribute__((address_space(3)))

// ---------- prep: Wt2/Wt3 transpose+bf16, zero deg + gsum (one kernel) ----------
__global__ __launch_bounds__(256) void k_prep(const float* __restrict__ W2,
                                              const float* __restrict__ W3,
                                              ushort* __restrict__ Wt2,
                                              ushort* __restrict__ Wt3,
                                              int* __restrict__ deg,
                                              float* __restrict__ gsum) {
  __shared__ float tl[32][33];
  int b = blockIdx.x, t = threadIdx.x;
  int tx = t & 31, ty = t >> 5;
  if (b < 256) {  // Wt2: K=512, N=512
    int bn = (b & 15) * 32, bk = (b >> 4) * 32;
    for (int i = ty; i < 32; i += 8) tl[i][tx] = W2[(size_t)(bk + i) * 512 + bn + tx];
    __syncthreads();
    for (int i = ty; i < 32; i += 8)
      Wt2[(size_t)(bn + i) * 512 + bk + tx] = f2bf(tl[tx][i]);
  } else if (b < 320) {  // Wt3: K=512, N=128
    int bb = b - 256;
    int bn = (bb & 3) * 32, bk = (bb >> 2) * 32;
    for (int i = ty; i < 32; i += 8) tl[i][tx] = W3[(size_t)(bk + i) * 128 + bn + tx];
    __syncthreads();
    for (int i = ty; i < 32; i += 8)
      Wt3[(size_t)(bn + i) * 512 + bk + tx] = f2bf(tl[tx][i]);
  } else {  // zero deg (196 blocks); first block also zeroes gsum
    int b2 = b - 320;
    int idx = b2 * 256 + t;
    if (idx < NN) deg[idx] = 0;
    if (b2 == 0 && t < HID) gsum[t] = 0.f;
  }
}

// ---------- CSR build ----------
__global__ void k_deg(const int* __restrict__ ei, int* __restrict__ deg) {
  int e = blockIdx.x * blockDim.x + threadIdx.x;
  if (e < NE) atomicAdd(&deg[ei[NE + e]], 1);
}

__global__ void k_scan(const int* __restrict__ deg, int* __restrict__ row_ptr,
                       int* __restrict__ cursor) {
  const int T = 1024;
  const int CH = (NN + T - 1) / T;
  __shared__ int ssum[T];
  int t = threadIdx.x;
  int base = t * CH;
  int s = 0;
  for (int i = 0; i < CH; i++) {
    int idx = base + i;
    if (idx < NN) s += deg[idx];
  }
  ssum[t] = s;
  __syncthreads();
  for (int off = 1; off < T; off <<= 1) {
    int v = (t >= off) ? ssum[t - off] : 0;
    __syncthreads();
    ssum[t] += v;
    __syncthreads();
  }
  int run = ssum[t] - s;
  for (int i = 0; i < CH; i++) {
    int idx = base + i;
    if (idx < NN) {
      row_ptr[idx] = run;
      cursor[idx] = run;
      run += deg[idx];
    }
  }
  if (t == 0) row_ptr[NN] = ssum[T - 1];
}

__global__ void k_scatter(const int* __restrict__ ei, int* __restrict__ cursor,
                          int* __restrict__ csr_src) {
  int e = blockIdx.x * blockDim.x + threadIdx.x;
  if (e < NE) {
    int d = ei[NE + e];
    int pos = atomicAdd(&cursor[d], 1);
    csr_src[pos] = ei[e];
  }
}

// ---------- layer 1: per-node attention scores from raw x (vsd inlined) ----------
__global__ __launch_bounds__(256) void k_axv(const float* __restrict__ x,
                                             const float* __restrict__ W1,
                                             const float* __restrict__ as1,
                                             const float* __restrict__ ad1,
                                             float* __restrict__ asrc,
                                             float* __restrict__ adst) {
  __shared__ float svs[44], svd[44];
  int t = threadIdx.x;
  if (t < 88) {  // collapsed vectors v_s/v_d[k][h] = sum_c W1[k,h*128+c]*a[h,c]
    int side = t & 1, kh = t >> 1;
    int k = kh >> 2, h = kh & 3;
    const float* av = side ? ad1 : as1;
    float s = 0.f;
    for (int c = 0; c < HID; c++) s += W1[k * 512 + h * HID + c] * av[h * HID + c];
    if (side)
      svd[kh] = s;
    else
      svs[kh] = s;
  }
  __syncthreads();
  int n = blockIdx.x * 256 + t;
  if (n >= NN) return;
  float xr[F_IN];
#pragma unroll
  for (int k = 0; k < F_IN; k++) xr[k] = x[n * F_IN + k];
  float s[4] = {}, dd[4] = {};
#pragma unroll
  for (int k = 0; k < F_IN; k++)
#pragma unroll
    for (int h = 0; h < 4; h++) {
      s[h] += xr[k] * svs[k * 4 + h];
      dd[h] += xr[k] * svd[k * 4 + h];
    }
  *(f32x4*)(asrc + n * 4) = f32x4{s[0], s[1], s[2], s[3]};
  *(f32x4*)(adst + n * 4) = f32x4{dd[0], dd[1], dd[2], dd[3]};
}

// ---------- layer 1: aggregate RAW x -> P (in LDS) -> out = elu(P@W1 + b1) ----------
__global__ __launch_bounds__(256) void k_aggpre(
    const float* __restrict__ x, const float* __restrict__ asrc,
    const float* __restrict__ adst, const int* __restrict__ row_ptr,
    const int* __restrict__ csr_src, const float* __restrict__ W1,
    const float* __restrict__ b1, ushort* __restrict__ out) {
  const int CAP = 64;
  __shared__ float sW[F_IN * 512];  // 22.5 KB
  __shared__ int src_c[4][CAP];
  __shared__ float ea[4][CAP * 4];
  __shared__ float sP[4][44];
  int t = threadIdx.x, lane = t & 63, wv = t >> 6;
  for (int i = t; i < F_IN * 512; i += 256) sW[i] = W1[i];  // used after barrier
  int d = blockIdx.x * 4 + wv;
  int start = row_ptr[d], deg = row_ptr[d + 1] - start;
  int dcap = min(deg, CAP);
  for (int i = lane; i < dcap; i += 64) src_c[wv][i] = csr_src[start + i];
  wave_fence();
  int hh = lane & 3;
  float adh = adst[d * 4 + hh];
  float m = MNEG, s = 0.f;
  int deg4 = deg * 4;
  for (int i = lane; i < deg4; i += 64) {
    int k = i >> 2;
    int sn = (k < CAP) ? src_c[wv][k] : csr_src[start + k];
    float v = lrelu(asrc[sn * 4 + hh] + adh);
    if (k < CAP) ea[wv][i] = v;
    float nm = fmaxf(m, v);
    s = s * __expf(m - nm) + __expf(v - nm);
    m = nm;
  }
#pragma unroll
  for (int off = 4; off < 64; off <<= 1) {
    float m2 = __shfl_xor(m, off);
    float s2 = __shfl_xor(s, off);
    float nm = fmaxf(m, m2);
    s = s * __expf(m - nm) + s2 * __expf(m2 - nm);
    m = nm;
  }
  float sinv = (s > 0.f) ? 1.f / s : 0.f;
  int dc4 = dcap * 4;
  for (int i = lane; i < dc4; i += 64) ea[wv][i] = __expf(ea[wv][i] - m) * sinv;
  wave_fence();
  // pass 2: lanes 0..43 own (h,k); unroll-4 edges
  int hq = lane / F_IN;
  int k = lane - hq * F_IN;
  int h = hq & 3;
  float mh = __shfl(m, h), sih = __shfl(sinv, h);
  float adh2 = adst[d * 4 + h];
  float acc = 0.f;
#define GETP(i, SN, A)                                                \
  do {                                                                \
    int kk_ = e + (i);                                                \
    if (kk_ < CAP) {                                                  \
      SN = src_c[wv][kk_];                                            \
      A = ea[wv][kk_ * 4 + h];                                        \
    } else {                                                          \
      SN = csr_src[start + kk_];                                      \
      A = __expf(lrelu(asrc[SN * 4 + h] + adh2) - mh) * sih;          \
    }                                                                 \
  } while (0)
  int e = 0;
  for (; e + 4 <= deg; e += 4) {
    int sn0, sn1, sn2, sn3;
    float a0, a1, a2, a3;
    GETP(0, sn0, a0);
    GETP(1, sn1, a1);
    GETP(2, sn2, a2);
    GETP(3, sn3, a3);
    float x0 = x[sn0 * F_IN + k];
    float x1 = x[sn1 * F_IN + k];
    float x2 = x[sn2 * F_IN + k];
    float x3 = x[sn3 * F_IN + k];
    acc += a0 * x0 + a1 * x1 + a2 * x2 + a3 * x3;
  }
  for (; e < deg; e++) {
    int sn;
    float a;
    GETP(0, sn, a);
    acc += a * x[sn * F_IN + k];
  }
#undef GETP
  if (lane < 44) sP[wv][lane] = acc;
  __syncthreads();  // sP + sW ready
  // fused layer-1 GEMM: thread -> node (wv), cols lane*8..+7 (one head per lane)
  int j0 = lane * 8;
  int hj = j0 >> 7;
  float pv[F_IN];
#pragma unroll
  for (int kk = 0; kk < F_IN; kk++) pv[kk] = sP[wv][hj * F_IN + kk];
  float o[8];
#pragma unroll
  for (int jj = 0; jj < 8; jj++) o[jj] = b1[j0 + jj];
#pragma unroll
  for (int kk = 0; kk < F_IN; kk++) {
    float4 wa = *(const float4*)&sW[kk * 512 + j0];
    float4 wb = *(const float4*)&sW[kk * 512 + j0 + 4];
    float p = pv[kk];
    o[0] += p * wa.x;
    o[1] += p * wa.y;
    o[2] += p * wa.z;
    o[3] += p * wa.w;
    o[4] += p * wb.x;
    o[5] += p * wb.y;
    o[6] += p * wb.z;
    o[7] += p * wb.w;
  }
  unsigned pk[4];
#pragma unroll
  for (int j = 0; j < 4; j++) {
    float e0 = elu1(o[2 * j]);
    float e1 = elu1(o[2 * j + 1]);
    pk[j] = (unsigned)f2bf(e0) | ((unsigned)f2bf(e1) << 16);
  }
  *(uint4*)(out + (size_t)d * 512 + j0) = make_uint4(pk[0], pk[1], pk[2], pk[3]);
}

// ---------- bf16 MFMA GEMM, 128x128 tile (layers 2 and 3; proven replay-safe) ----------
#define TM 128
#define TN 128
#define TK 64
__global__ __launch_bounds__(256) void k_mfma(const ushort* __restrict__ A,
                                              const ushort* __restrict__ Bt,
                                              ushort* __restrict__ C,
                                              int M, int N, int K, int H) {
  __shared__ ushort lds[TM * TK + TN * TK];
  ushort* As = lds;
  ushort* Bs = lds + TM * TK;
  int tid = threadIdx.x;
  int lane = tid & 63, wv = tid >> 6;
  int wr = wv >> 1, wc = wv & 1;
  int nwg = gridDim.x;
  int q = nwg >> 3, rr = nwg & 7;
  int xcd = blockIdx.x & 7, off8 = blockIdx.x >> 3;
  int lid = (xcd < rr ? xcd * (q + 1) : rr * (q + 1) + (xcd - rr) * q) + off8;
  int bm = lid / H, hy = lid - bm * H;
  int bm0 = bm * TM, bn0 = hy * TN;
  int l15 = lane & 15, l4 = lane >> 4;
  f32x4 acc[4][4] = {};
  for (int k0 = 0; k0 < K; k0 += TK) {
#pragma unroll
    for (int it = 0; it < 4; ++it) {
      int chunk = it * 4 + wv;
      int pbase = chunk * 1024;
      int p = pbase + lane * 16;
      int prow = p >> 7;
      int lblk = ((p >> 4) & 7) ^ (prow & 7);
      int gr = bm0 + prow;
      gr = gr < M ? gr : M - 1;
      __builtin_amdgcn_global_load_lds(
          (const AS1 void*)(A + (size_t)gr * K + (k0 + lblk * 8)),
          (AS3 void*)((char*)As + pbase), 16, 0, 0);
      int gb = bn0 + prow;
      __builtin_amdgcn_global_load_lds(
          (const AS1 void*)(Bt + (size_t)gb * K + (k0 + lblk * 8)),
          (AS3 void*)((char*)Bs + pbase), 16, 0, 0);
    }
    __syncthreads();
#pragma unroll
    for (int kk = 0; kk < 2; ++kk) {
      int cb = kk * 4 + l4;
      short8 af[4], bfr[4];
#pragma unroll
      for (int m = 0; m < 4; ++m) {
        int row = wr * 64 + m * 16 + l15;
        af[m] = *(const short8*)((const char*)As + row * 128 + ((cb ^ (row & 7)) << 4));
      }
#pragma unroll
      for (int n = 0; n < 4; ++n) {
        int row = wc * 64 + n * 16 + l15;
        bfr[n] = *(const short8*)((const char*)Bs + row * 128 + ((cb ^ (row & 7)) << 4));
      }
#pragma unroll
      for (int m = 0; m < 4; ++m)
#pragma unroll
        for (int n = 0; n < 4; ++n)
          acc[m][n] = __builtin_amdgcn_mfma_f32_16x16x32_bf16(af[m], bfr[n], acc[m][n], 0, 0, 0);
    }
    __syncthreads();
  }
#pragma unroll
  for (int m = 0; m < 4; ++m) {
#pragma unroll
    for (int r = 0; r < 4; ++r) {
      int row = bm0 + wr * 64 + m * 16 + l4 * 4 + r;
      if (row < M) {
#pragma unroll
        for (int n = 0; n < 4; ++n) {
          int col = bn0 + wc * 64 + n * 16 + l15;
          C[(size_t)row * N + col] = f2bf(acc[m][n][r]);
        }
      }
    }
  }
}

// ---------- attention coefficients from transformed features (layers 2,3) ----------
template <int H>
__global__ void k_alpha(const ushort* __restrict__ h, const float* __restrict__ a_src,
                        const float* __restrict__ a_dst, float* __restrict__ asrc,
                        float* __restrict__ adst) {
  int t = threadIdx.x;  // 256
  int lane = t & 63;
  int n_g, h_g;
  if (H == 4) {
    n_g = blockIdx.x * 4 + (t >> 6);
    h_g = lane >> 4;
  } else {
    n_g = blockIdx.x * 16 + (t >> 4);
    h_g = 0;
  }
  if (n_g >= NN) return;
  int cl = lane & 15;
  short8 hv = *(const short8*)(h + (size_t)n_g * (H * 128) + h_g * 128 + cl * 8);
  const float* as = a_src + h_g * 128 + cl * 8;
  const float* ad = a_dst + h_g * 128 + cl * 8;
  float s1 = 0.f, s2 = 0.f;
#pragma unroll
  for (int j = 0; j < 8; j++) {
    float v = bf2f((ushort)hv[j]);
    s1 += v * as[j];
    s2 += v * ad[j];
  }
#pragma unroll
  for (int off = 1; off < 16; off <<= 1) {
    s1 += __shfl_xor(s1, off);
    s2 += __shfl_xor(s2, off);
  }
  if (cl == 0) {
    asrc[n_g * H + h_g] = s1;
    adst[n_g * H + h_g] = s2;
  }
}

// ---------- layer-2 aggregate: wave-per-node, H=4, unroll-2 gather ----------
// (unroll-2 is the sweet spot: 28 VGPR / ~86% occupancy; unroll-4 was 48 VGPR
//  / 51% occupancy and 10us slower — round-7 post-mortem)
__global__ __launch_bounds__(256) void k_agg4w(
    const ushort* __restrict__ h, const float* __restrict__ asrc,
    const float* __restrict__ adst, const int* __restrict__ row_ptr,
    const int* __restrict__ csr_src, const float* __restrict__ bias,
    ushort* __restrict__ out) {
  const int CAP = 64;
  __shared__ int src_c[4][CAP];
  __shared__ float ea[4][CAP * 4];
  int t = threadIdx.x, lane = t & 63, wv = t >> 6;
  int d = blockIdx.x * 4 + wv;
  int start = row_ptr[d], deg = row_ptr[d + 1] - start;
  int dcap = min(deg, CAP);
  for (int i = lane; i < dcap; i += 64) src_c[wv][i] = csr_src[start + i];
  wave_fence();
  int hh = lane & 3;
  float adh = adst[d * 4 + hh];
  float m = MNEG, s = 0.f;
  int deg4 = deg * 4;
  for (int i = lane; i < deg4; i += 64) {
    int k = i >> 2;
    int sn = (k < CAP) ? src_c[wv][k] : csr_src[start + k];
    float v = lrelu(asrc[sn * 4 + hh] + adh);
    if (k < CAP) ea[wv][i] = v;
    float nm = fmaxf(m, v);
    s = s * __expf(m - nm) + __expf(v - nm);
    m = nm;
  }
#pragma unroll
  for (int off = 4; off < 64; off <<= 1) {
    float m2 = __shfl_xor(m, off);
    float s2 = __shfl_xor(s, off);
    float nm = fmaxf(m, m2);
    s = s * __expf(m - nm) + s2 * __expf(m2 - nm);
    m = nm;
  }
  float sinv = (s > 0.f) ? 1.f / s : 0.f;
  int dc4 = dcap * 4;
  for (int i = lane; i < dc4; i += 64) ea[wv][i] = __expf(ea[wv][i] - m) * sinv;
  wave_fence();
  int hl = lane >> 4;
  float mh = __shfl(m, hl), sih = __shfl(sinv, hl);
  float adh2 = adst[d * 4 + hl];
  float acc0[8] = {}, acc1[8] = {};
  int k = 0;
  for (; k + 2 <= deg; k += 2) {
    int sn0, sn1;
    float a0, a1;
    if (k < CAP) {
      sn0 = src_c[wv][k];
      a0 = ea[wv][k * 4 + hl];
    } else {
      sn0 = csr_src[start + k];
      a0 = __expf(lrelu(asrc[sn0 * 4 + hl] + adh2) - mh) * sih;
    }
    if (k + 1 < CAP) {
      sn1 = src_c[wv][k + 1];
      a1 = ea[wv][(k + 1) * 4 + hl];
    } else {
      sn1 = csr_src[start + k + 1];
      a1 = __expf(lrelu(asrc[sn1 * 4 + hl] + adh2) - mh) * sih;
    }
    short8 v0 = *(const short8*)(h + (size_t)sn0 * 512 + lane * 8);
    short8 v1 = *(const short8*)(h + (size_t)sn1 * 512 + lane * 8);
#pragma unroll
    for (int j = 0; j < 8; j++) acc0[j] += a0 * bf2f((ushort)v0[j]);
#pragma unroll
    for (int j = 0; j < 8; j++) acc1[j] += a1 * bf2f((ushort)v1[j]);
  }
  if (k < deg) {
    int sn;
    float a;
    if (k < CAP) {
      sn = src_c[wv][k];
      a = ea[wv][k * 4 + hl];
    } else {
      sn = csr_src[start + k];
      a = __expf(lrelu(asrc[sn * 4 + hl] + adh2) - mh) * sih;
    }
    short8 v0 = *(const short8*)(h + (size_t)sn * 512 + lane * 8);
#pragma unroll
    for (int j = 0; j < 8; j++) acc0[j] += a * bf2f((ushort)v0[j]);
  }
  const float* bp = bias + lane * 8;
  unsigned pk[4];
#pragma unroll
  for (int j = 0; j < 4; j++) {
    float o0 = elu1(acc0[2 * j] + acc1[2 * j] + bp[2 * j]);
    float o1 = elu1(acc0[2 * j + 1] + acc1[2 * j + 1] + bp[2 * j + 1]);
    pk[j] = (unsigned)f2bf(o0) | ((unsigned)f2bf(o1) << 16);
  }
  *(uint4*)(out + (size_t)d * 512 + lane * 8) = make_uint4(pk[0], pk[1], pk[2], pk[3]);
}

// ---------- layer-3 aggregate: wave-per-node, 16-lane x 4-edge-slot, 16B loads ----------
__global__ __launch_bounds__(256) void k_agg1w(
    const ushort* __restrict__ h, const float* __restrict__ asrc,
    const float* __restrict__ adst, const int* __restrict__ row_ptr,
    const int* __restrict__ csr_src, const float* __restrict__ bias,
    ushort* __restrict__ out) {
  const int CAP = 64;
  __shared__ int src_c[4][CAP];
  __shared__ float ea[4][CAP];
  int t = threadIdx.x, lane = t & 63, wv = t >> 6;
  int slot = lane >> 4, cl = lane & 15;
  int d = blockIdx.x * 4 + wv;
  int start = row_ptr[d], deg = row_ptr[d + 1] - start;
  int dcap = min(deg, CAP);
  for (int i = lane; i < dcap; i += 64) src_c[wv][i] = csr_src[start + i];
  wave_fence();
  float adh = adst[d];
  float m = MNEG, s = 0.f;
  for (int i = lane; i < deg; i += 64) {
    int sn = (i < CAP) ? src_c[wv][i] : csr_src[start + i];
    float v = lrelu(asrc[sn] + adh);
    if (i < CAP) ea[wv][i] = v;
    float nm = fmaxf(m, v);
    s = s * __expf(m - nm) + __expf(v - nm);
    m = nm;
  }
#pragma unroll
  for (int off = 1; off < 64; off <<= 1) {
    float m2 = __shfl_xor(m, off);
    float s2 = __shfl_xor(s, off);
    float nm = fmaxf(m, m2);
    s = s * __expf(m - nm) + s2 * __expf(m2 - nm);
    m = nm;
  }
  float sinv = (s > 0.f) ? 1.f / s : 0.f;
  for (int i = lane; i < dcap; i += 64) ea[wv][i] = __expf(ea[wv][i] - m) * sinv;
  wave_fence();
#define GET1(KK, SN, A)                                               \
  do {                                                                \
    if ((KK) < CAP) {                                                 \
      SN = src_c[wv][KK];                                             \
      A = ea[wv][KK];                                                 \
    } else {                                                          \
      SN = csr_src[start + (KK)];                                     \
      A = __expf(lrelu(asrc[SN] + adh) - m) * sinv;                   \
    }                                                                 \
  } while (0)
  float acc0[8] = {}, acc1[8] = {};
  int k = slot;
  for (; k + 4 < deg; k += 8) {
    int sn0, sn1;
    float a0, a1;
    GET1(k, sn0, a0);
    GET1(k + 4, sn1, a1);
    short8 v0 = *(const short8*)(h + (size_t)sn0 * 128 + cl * 8);
    short8 v1 = *(const short8*)(h + (size_t)sn1 * 128 + cl * 8);
#pragma unroll
    for (int j = 0; j < 8; j++) acc0[j] += a0 * bf2f((ushort)v0[j]);
#pragma unroll
    for (int j = 0; j < 8; j++) acc1[j] += a1 * bf2f((ushort)v1[j]);
  }
  for (; k < deg; k += 4) {
    int sn;
    float a;
    GET1(k, sn, a);
    short8 v0 = *(const short8*)(h + (size_t)sn * 128 + cl * 8);
#pragma unroll
    for (int j = 0; j < 8; j++) acc0[j] += a * bf2f((ushort)v0[j]);
  }
#undef GET1
#pragma unroll
  for (int j = 0; j < 8; j++) {
    float v = acc0[j] + acc1[j];
    v += __shfl_xor(v, 16);
    v += __shfl_xor(v, 32);
    acc0[j] = v;
  }
  if (slot == 0) {
    const float* bp = bias + cl * 8;
    unsigned pk[4];
#pragma unroll
    for (int j = 0; j < 4; j++) {
      float o0 = acc0[2 * j] + bp[2 * j];
      float o1 = acc0[2 * j + 1] + bp[2 * j + 1];
      pk[j] = (unsigned)f2bf(o0) | ((unsigned)f2bf(o1) << 16);
    }
    *(uint4*)(out + (size_t)d * 128 + cl * 8) = make_uint4(pk[0], pk[1], pk[2], pk[3]);
  }
}

// ---------- graph mean + heads ----------
__global__ __launch_bounds__(256) void k_colsum(const ushort* __restrict__ h3,
                                                float* __restrict__ gsum) {
  __shared__ float partial[16 * 128];
  int t = threadIdx.x;
  int rg = t >> 4, cl = t & 15;
  int nb = gridDim.x;
  int per = (NN + nb - 1) / nb;
  int r0 = blockIdx.x * per, r1 = min(NN, r0 + per);
  float acc[8] = {};
  for (int r = r0 + rg; r < r1; r += 16) {
    short8 hv = *(const short8*)(h3 + (size_t)r * 128 + cl * 8);
#pragma unroll
    for (int j = 0; j < 8; j++) acc[j] += bf2f((ushort)hv[j]);
  }
#pragma unroll
  for (int j = 0; j < 8; j++) partial[rg * 128 + cl * 8 + j] = acc[j];
  __syncthreads();
  if (t < 128) {
    float s = 0.f;
    for (int q = 0; q < 16; q++) s += partial[q * 128 + t];
    atomicAdd(&gsum[t], s);
  }
}

__global__ void k_head(const float* __restrict__ gsum, const ushort* __restrict__ h3,
                       const int* __restrict__ curp, const float* __restrict__ pw1,
                       const float* __restrict__ pb1, const float* __restrict__ pw2,
                       const float* __restrict__ pb2, const float* __restrict__ vw1,
                       const float* __restrict__ vb1, const float* __restrict__ vw2,
                       const float* __restrict__ vb2, float* __restrict__ outp) {
  __shared__ float comb[HID], ph[HID], vh[HID];
  int t = threadIdx.x;  // 128
  int cur = curp[0];
  comb[t] = gsum[t] * (1.f / NN) + bf2f(h3[(size_t)cur * HID + t]);
  __syncthreads();
  float accp = pb1[t], accv = vb1[t];
  for (int k = 0; k < HID; k++) {
    float cv = comb[k];
    accp += cv * pw1[k * HID + t];
    accv += cv * vw1[k * HID + t];
  }
  ph[t] = fmaxf(accp, 0.f);
  vh[t] = fmaxf(accv, 0.f);
  __syncthreads();
  if (t < 6) {
    float a = pb2[t];
    for (int k = 0; k < HID; k++) a += ph[k] * pw2[k * 6 + t];
    outp[t] = a;
  }
  if (t == 6) {
    float a = vb2[0];
    for (int k = 0; k < HID; k++) a += vh[k] * vw2[k];
    outp[6] = a;
  }
}

extern "C" void kernel_launch(void* const* d_in, const int* in_sizes, int n_in,
                              void* d_out, int out_size, void* d_ws, size_t ws_size,
                              hipStream_t stream) {
  const float* x = (const float*)d_in[0];
  const int* ei = (const int*)d_in[1];
  const int* cur = (const int*)d_in[2];
  const float* W1 = (const float*)d_in[3];
  const float* as1 = (const float*)d_in[4];
  const float* ad1 = (const float*)d_in[5];
  const float* b1 = (const float*)d_in[6];
  const float* W2 = (const float*)d_in[7];
  const float* as2 = (const float*)d_in[8];
  const float* ad2 = (const float*)d_in[9];
  const float* b2 = (const float*)d_in[10];
  const float* W3 = (const float*)d_in[11];
  const float* as3 = (const float*)d_in[12];
  const float* ad3 = (const float*)d_in[13];
  const float* b3 = (const float*)d_in[14];
  const float* pw1 = (const float*)d_in[15];
  const float* pb1 = (const float*)d_in[16];
  const float* pw2 = (const float*)d_in[17];
  const float* pb2 = (const float*)d_in[18];
  const float* vw1 = (const float*)d_in[19];
  const float* vb1 = (const float*)d_in[20];
  const float* vw2 = (const float*)d_in[21];
  const float* vb2 = (const float*)d_in[22];
  float* out = (float*)d_out;

  char* w = (char*)d_ws;
  ushort* G = (ushort*)w;    w += (size_t)NN * 512 * 2;
  ushort* Abuf = (ushort*)w; w += (size_t)NN * 512 * 2;
  ushort* Wt2 = (ushort*)w;  w += (size_t)512 * 512 * 2;
  ushort* Wt3 = (ushort*)w;  w += (size_t)128 * 512 * 2;
  float* asrc = (float*)w;   w += (size_t)NN * 4 * 4;
  float* adst = (float*)w;   w += (size_t)NN * 4 * 4;
  int* deg = (int*)w;        w += (size_t)NN * 4;
  int* cursor = (int*)w;     w += (size_t)NN * 4;
  int* row_ptr = (int*)w;    w += (size_t)(NN + 1) * 4;
  int* csr_src = (int*)w;    w += (size_t)NE * 4;
  float* gsum = (float*)w;   w += (size_t)HID * 4;

  // prep: Wt2 (256 blocks) + Wt3 (64) + zero deg/gsum (196)
  k_prep<<<516, 256, 0, stream>>>(W2, W3, Wt2, Wt3, deg, gsum);

  // CSR
  k_deg<<<(NE + 255) / 256, 256, 0, stream>>>(ei, deg);
  k_scan<<<1, 1024, 0, stream>>>(deg, row_ptr, cursor);
  k_scatter<<<(NE + 255) / 256, 256, 0, stream>>>(ei, cursor, csr_src);

  const int GB = (NN + TM - 1) / TM;  // 391

  // Layer 1: scores from raw x, aggregate raw x, fused 11->512 GEMM + ELU
  k_axv<<<(NN + 255) / 256, 256, 0, stream>>>(x, W1, as1, ad1, asrc, adst);
  k_aggpre<<<NN / 4, 256, 0, stream>>>(x, asrc, adst, row_ptr, csr_src, W1, b1, Abuf);

  // Layer 2: bf16 MFMA (128x128, XCD swizzle), alpha, wave-per-node aggregate
  k_mfma<<<GB * 4, 256, 0, stream>>>(Abuf, Wt2, G, NN, 512, 512, 4);
  k_alpha<4><<<(NN + 3) / 4, 256, 0, stream>>>(G, as2, ad2, asrc, adst);
  k_agg4w<<<NN / 4, 256, 0, stream>>>(G, asrc, adst, row_ptr, csr_src, b2, Abuf);

  // Layer 3: bf16 MFMA (128x128, proven), alpha, aggregate
  k_mfma<<<GB, 256, 0, stream>>>(Abuf, Wt3, G, NN, 128, 512, 1);
  k_alpha<1><<<(NN + 15) / 16, 256, 0, stream>>>(G, as3, ad3, asrc, adst);
  k_agg1w<<<NN / 4, 256, 0, stream>>>(G, asrc, adst, row_ptr, csr_src, b3, Abuf);

  // Heads
  k_colsum<<<256, 256, 0, stream>>>(Abuf, gsum);
  k_head<<<1, 128, 0, stream>>>(gsum, Abuf, cur, pw1, pb1, pw2, pb2, vw1, vb1, vw2, vb2, out);
}